// Round 6
// baseline (1889.035 us; speedup 1.0000x reference)
//
#include <hip/hip_runtime.h>

// ---------------------------------------------------------------------------
// RegressionGRU round 6. Layer 1 of the reference is dead code; only layer-0's
// final hidden state feeds the output head.
//
// Two-phase design:
//   Phase 1 (all 256 CUs): xg = x @ w_ih^T as bf16, pre-swizzled into d_ws so
//     each consumer thread's 24 acc-init values are 3 coalesced dwordx4 loads.
//   Phase 2 (persistent, 32 WGs x 512 thr): recurrence only. Per step: 48 hg
//     MFMA/wave (whh r,z register-resident 128 VGPRs; whh n in 128KB LDS),
//     gate math, bf16 h double-buffer in LDS. xg(t+1) prefetched during step t.
//
// R5 counters showed VALU-issue-bound (active-CU VALUBusy 54%, 3.7x static
// estimate): arch-VGPR pressure (whh 128 + wi 48 + x 16 > 128 arch) forced
// AGPR shuttling. Dropping wi/x from the loop removes 64 regs + ~60 VALU and
// 12 MFMA per wave-step. Fallback to the proven R5 kernel if ws too small.
// ---------------------------------------------------------------------------

typedef __attribute__((ext_vector_type(8))) short short8;
typedef __attribute__((ext_vector_type(4))) float floatx4;

#define T_LEN 512
#define I_DIM 64
#define H_DIM 256
#define NB 16      // batch rows per WG (one MFMA M-tile)
#define NWG 32     // 512 / 16

#define XG_OFF   131072                       // wih_bf region (96KB) rounded up
#define XG_BYTES ((size_t)T_LEN * 32 * 3 * 512 * 16)  // 384 MiB

__device__ __forceinline__ unsigned short f2bf(float f) {
    union { float f; unsigned u; } v; v.f = f;
    return (unsigned short)((v.u + 0x7FFFu + ((v.u >> 16) & 1u)) >> 16);
}

__device__ __forceinline__ float bf2f(unsigned short u) {
    union { unsigned u; float f; } v; v.u = ((unsigned)u) << 16;
    return v.f;
}

__device__ __forceinline__ short8 pack8v(floatx4 a, floatx4 b) {
    short8 r;
    r[0] = (short)f2bf(a[0]); r[1] = (short)f2bf(a[1]);
    r[2] = (short)f2bf(a[2]); r[3] = (short)f2bf(a[3]);
    r[4] = (short)f2bf(b[0]); r[5] = (short)f2bf(b[1]);
    r[6] = (short)f2bf(b[2]); r[7] = (short)f2bf(b[3]);
    return r;
}

__device__ __forceinline__ float sigm(float a) {
    return 1.0f / (1.0f + __expf(-a));
}

// w_ih fp32 [768x64] -> bf16 in d_ws, blocked: block ((w*6+g)*2+kx)*64+lane.
__global__ void cvt_wih_kernel(const float* __restrict__ w,
                               unsigned short* __restrict__ o) {
    int i = blockIdx.x * 256 + threadIdx.x;
    if (i < 6144) {
        const int l  = i & 63;
        const int kx = (i >> 6) & 1;
        const int g  = (i >> 7) % 6;
        const int wv = (i >> 7) / 6;
        const int row = (g >> 1) * 256 + wv * 32 + (g & 1) * 16 + (l & 15);
        const int col = kx * 32 + (l >> 4) * 8;
        const float* p = w + row * I_DIM + col;
        *(short8*)&o[i * 8] = pack8v(*(const floatx4*)p,
                                     *(const floatx4*)(p + 4));
    }
}

// ---------------------------------------------------------------------------
// Phase 1: xg[t][wgb][plane(0=r,1=z,2=n)][tid'][8 bf16]
//   plane p, consumer thread tid' = wp*64 + quad*16 + m16 gets
//   [i0:r0..3 | i1:r0..3] for units wp*32 + i*16 + m16, batch wgb*16+quad*4+r.
// Grid: 1024 WGs (32 wgb x 32 tgrp) x 256 thr; wave handles 4 consecutive t.
// ---------------------------------------------------------------------------
__global__ __launch_bounds__(256) void xg_kernel(
    const float* __restrict__ x,
    const unsigned short* __restrict__ wih_bf,
    unsigned short* __restrict__ xg)
{
    const int tid  = threadIdx.x;
    const int wv   = tid >> 6;      // 0..3
    const int lane = tid & 63;
    const int m16  = lane & 15;
    const int quad = lane >> 4;
    const int wgb  = blockIdx.x & 31;
    const int t0   = (blockIdx.x >> 5) * 16 + wv * 4;

    // A-frags for 4 t values x 2 K-halves
    short8 af0[4], af1[4];
    #pragma unroll
    for (int j = 0; j < 4; ++j) {
        const float* xp = x + ((long)(wgb * 16 + m16) * T_LEN + (t0 + j)) * I_DIM
                            + quad * 8;
        af0[j] = pack8v(*(const floatx4*)xp,        *(const floatx4*)(xp + 4));
        af1[j] = pack8v(*(const floatx4*)(xp + 32), *(const floatx4*)(xp + 36));
    }

    #pragma unroll 1
    for (int wp = 0; wp < 8; ++wp) {
        #pragma unroll 1
        for (int gate = 0; gate < 3; ++gate) {
            const int gb = (wp * 6 + gate * 2) * 2;   // block base for i=0,kx=0
            short8 b00 = *(const short8*)&wih_bf[((gb + 0) * 64 + lane) * 8];
            short8 b01 = *(const short8*)&wih_bf[((gb + 1) * 64 + lane) * 8];
            short8 b10 = *(const short8*)&wih_bf[((gb + 2) * 64 + lane) * 8];
            short8 b11 = *(const short8*)&wih_bf[((gb + 3) * 64 + lane) * 8];
            #pragma unroll
            for (int j = 0; j < 4; ++j) {
                floatx4 a0 = {0, 0, 0, 0}, a1 = {0, 0, 0, 0};
                a0 = __builtin_amdgcn_mfma_f32_16x16x32_bf16(af0[j], b00, a0, 0, 0, 0);
                a0 = __builtin_amdgcn_mfma_f32_16x16x32_bf16(af1[j], b01, a0, 0, 0, 0);
                a1 = __builtin_amdgcn_mfma_f32_16x16x32_bf16(af0[j], b10, a1, 0, 0, 0);
                a1 = __builtin_amdgcn_mfma_f32_16x16x32_bf16(af1[j], b11, a1, 0, 0, 0);
                short8 pk;
                pk[0] = (short)f2bf(a0[0]); pk[1] = (short)f2bf(a0[1]);
                pk[2] = (short)f2bf(a0[2]); pk[3] = (short)f2bf(a0[3]);
                pk[4] = (short)f2bf(a1[0]); pk[5] = (short)f2bf(a1[1]);
                pk[6] = (short)f2bf(a1[2]); pk[7] = (short)f2bf(a1[3]);
                // ushort offset: (((t*32+wgb)*3+gate)*512 + wp*64+lane) * 8
                long off = ((((long)(t0 + j) * 32 + wgb) * 3 + gate) * 512
                            + wp * 64 + lane) * 8;
                *(short8*)&xg[off] = pk;
            }
        }
    }
}

// ---------------------------------------------------------------------------
// Phase 2: persistent recurrence (fast path, xg precomputed)
// ---------------------------------------------------------------------------
__global__ __launch_bounds__(512, 1) void gru_kernel_xg(
    const unsigned short* __restrict__ xg,     // swizzled bf16 xg
    const float* __restrict__ w_hh,            // [768, 256]
    const float* __restrict__ b_ih,            // [768]
    const float* __restrict__ b_hh,            // [768]
    const float* __restrict__ w_lin,           // [256]
    const float* __restrict__ b_lin,           // [1]
    float* __restrict__ out)                   // [1024]
{
    __shared__ __align__(16) unsigned short whn_lds[8192 * 8]; // 128 KB
    __shared__ __align__(16) unsigned short hbf[1024 * 8];     // 16 KB dbuf

    const int tid  = threadIdx.x;
    const int wave = tid >> 6;
    const int lane = tid & 63;
    const int m16  = lane & 15;
    const int quad = lane >> 4;
    const int wg   = blockIdx.x;

    // ---- preload whh n-gate -> LDS, blocked: block ((w*2+g)*8+k)*64+lane --
    for (int b = tid; b < 8192; b += 512) {
        const int l = b & 63;
        const int k = (b >> 6) & 7;
        const int g = (b >> 9) & 1;
        const int w = b >> 10;
        const int row = 512 + w * 32 + g * 16 + (l & 15);
        const int col = k * 32 + (l >> 4) * 8;
        const float* p = w_hh + row * H_DIM + col;
        *(short8*)&whn_lds[b * 8] = pack8v(*(const floatx4*)p,
                                           *(const floatx4*)(p + 4));
    }
    for (int b = tid; b < 1024; b += 512)
        *(short8*)&hbf[b * 8] = (short8)0;

    // ---- persistent w_hh r,z B-fragments: 4 tiles x 8 K = 128 VGPRs ------
    short8 whh[4][8];
    #pragma unroll
    for (int g = 0; g < 4; ++g) {
        const int row = (g >> 1) * 256 + wave * 32 + (g & 1) * 16 + m16;
        const float* rp = w_hh + row * H_DIM;
        #pragma unroll
        for (int k = 0; k < 8; ++k) {
            const float* p = rp + k * 32 + quad * 8;
            whh[g][k] = pack8v(*(const floatx4*)p, *(const floatx4*)(p + 4));
        }
    }

    // ---- biases in registers (8) -----------------------------------------
    float brz[4], bhn[2], bxn[2];
    #pragma unroll
    for (int g = 0; g < 4; ++g) {
        const int u = wave * 32 + (g & 1) * 16 + m16;
        brz[g] = b_ih[(g >> 1) * 256 + u] + b_hh[(g >> 1) * 256 + u];
    }
    #pragma unroll
    for (int i = 0; i < 2; ++i) {
        const int u = wave * 32 + i * 16 + m16;
        bhn[i] = b_hh[512 + u];
        bxn[i] = b_ih[512 + u];
    }

    float h_old[8] = {0, 0, 0, 0, 0, 0, 0, 0};

    // xg plane addressing (ushort units): ((t*32+wg)*3+p)*4096 + tid*8
    const unsigned short* xgb = xg + (long)wg * 3 * 4096 + tid * 8;
    const long tstride = (long)32 * 3 * 4096;

    // prefetch t = 0
    short8 pf0 = *(const short8*)&xgb[0 * 4096];
    short8 pf1 = *(const short8*)&xgb[1 * 4096];
    short8 pf2 = *(const short8*)&xgb[2 * 4096];

    __syncthreads();

    #pragma unroll 1
    for (int t = 0; t < T_LEN; ++t) {
        // ---- init accumulators from prefetched xg ------------------------
        floatx4 acc[4], an[2], xnl[2];
        #pragma unroll
        for (int r = 0; r < 4; ++r) {
            acc[0][r] = bf2f((unsigned short)pf0[r]);
            acc[1][r] = bf2f((unsigned short)pf0[4 + r]);
            acc[2][r] = bf2f((unsigned short)pf1[r]);
            acc[3][r] = bf2f((unsigned short)pf1[4 + r]);
            xnl[0][r] = bf2f((unsigned short)pf2[r]);
            xnl[1][r] = bf2f((unsigned short)pf2[4 + r]);
        }
        an[0] = an[1] = (floatx4){0, 0, 0, 0};

        // ---- prefetch xg(t+1) (hidden under hg MFMA block) ---------------
        {
            const long tb = (long)((t + 1) & (T_LEN - 1)) * tstride;
            pf0 = *(const short8*)&xgb[tb + 0 * 4096];
            pf1 = *(const short8*)&xgb[tb + 1 * 4096];
            pf2 = *(const short8*)&xgb[tb + 2 * 4096];
        }

        // ---- hg: h @ w_hh^T; r,z from registers, n from LDS --------------
        const unsigned short* hb  = &hbf[(t & 1) * 512 * 8];
        const unsigned short* wnb = &whn_lds[(wave * 2 * 8 * 64 + lane) * 8];
        #pragma unroll
        for (int k = 0; k < 8; ++k) {
            short8 af  = *(const short8*)&hb[(k * 64 + lane) * 8];
            short8 wn0 = *(const short8*)&wnb[(k * 64) * 8];
            short8 wn1 = *(const short8*)&wnb[((8 + k) * 64) * 8];
            acc[0] = __builtin_amdgcn_mfma_f32_16x16x32_bf16(af, whh[0][k], acc[0], 0, 0, 0);
            acc[1] = __builtin_amdgcn_mfma_f32_16x16x32_bf16(af, whh[1][k], acc[1], 0, 0, 0);
            acc[2] = __builtin_amdgcn_mfma_f32_16x16x32_bf16(af, whh[2][k], acc[2], 0, 0, 0);
            acc[3] = __builtin_amdgcn_mfma_f32_16x16x32_bf16(af, whh[3][k], acc[3], 0, 0, 0);
            an[0]  = __builtin_amdgcn_mfma_f32_16x16x32_bf16(af, wn0, an[0], 0, 0, 0);
            an[1]  = __builtin_amdgcn_mfma_f32_16x16x32_bf16(af, wn1, an[1], 0, 0, 0);
        }

        // ---- gates + h update (lane-local; C: col=m16, row=quad*4+r) -----
        unsigned short* hbn = &hbf[((t + 1) & 1) * 512 * 8];
        #pragma unroll
        for (int i = 0; i < 2; ++i) {
            #pragma unroll
            for (int r = 0; r < 4; ++r) {
                const int idx = i * 4 + r;
                float rr = sigm(acc[i][r] + brz[i]);
                float zz = sigm(acc[2 + i][r] + brz[2 + i]);
                float av = xnl[i][r] + bxn[i] + rr * (an[i][r] + bhn[i]);
                float nn = 1.0f - 2.0f / (1.0f + __expf(2.0f * av)); // tanh
                float hn = (1.0f - zz) * nn + zz * h_old[idx];
                h_old[idx] = hn;
                hbn[(wave * 64 + (i * 2 + (m16 >> 3)) * 16 + quad * 4 + r) * 8
                    + (m16 & 7)] = f2bf(hn);
            }
        }
        __syncthreads();
    }

    // ---- epilogue: p = sigmoid(h_last . w_lin + b) -----------------------
    __syncthreads();
    float* hfin = (float*)hbf;
    #pragma unroll
    for (int i = 0; i < 2; ++i)
        #pragma unroll
        for (int r = 0; r < 4; ++r)
            hfin[(quad * 4 + r) * 256 + wave * 32 + i * 16 + m16] =
                h_old[i * 4 + r];
    __syncthreads();

    const int m = tid >> 5, j = tid & 31;
    float s = 0.0f;
    #pragma unroll
    for (int c = 0; c < 8; ++c)
        s += hfin[m * 256 + j + c * 32] * w_lin[j + c * 32];
    #pragma unroll
    for (int d = 16; d > 0; d >>= 1) s += __shfl_down(s, d, 32);
    if (j == 0) {
        float p = sigm(s + b_lin[0]);
        const int b = wg * NB + m;
        out[2 * b]     = p;
        out[2 * b + 1] = 1.0f - p;
    }
}

// ---------------------------------------------------------------------------
// Fallback (R5 kernel, proven): used when ws_size can't hold xg.
// ---------------------------------------------------------------------------
__global__ __launch_bounds__(512, 1) void gru_kernel(
    const float* __restrict__ x,
    const float* __restrict__ w_hh,
    const float* __restrict__ b_ih,
    const float* __restrict__ b_hh,
    const unsigned short* __restrict__ wih_ws,
    const float* __restrict__ w_lin,
    const float* __restrict__ b_lin,
    float* __restrict__ out)
{
    __shared__ __align__(16) unsigned short whn_lds[8192 * 8];
    __shared__ __align__(16) unsigned short hbf[1024 * 8];

    const int tid  = threadIdx.x;
    const int wave = tid >> 6;
    const int lane = tid & 63;
    const int m16  = lane & 15;
    const int quad = lane >> 4;
    const int wg   = blockIdx.x;

    for (int b = tid; b < 8192; b += 512) {
        const int l = b & 63;
        const int k = (b >> 6) & 7;
        const int g = (b >> 9) & 1;
        const int w = b >> 10;
        const int row = 512 + w * 32 + g * 16 + (l & 15);
        const int col = k * 32 + (l >> 4) * 8;
        const float* p = w_hh + row * H_DIM + col;
        *(short8*)&whn_lds[b * 8] = pack8v(*(const floatx4*)p,
                                           *(const floatx4*)(p + 4));
    }
    for (int b = tid; b < 1024; b += 512)
        *(short8*)&hbf[b * 8] = (short8)0;

    short8 whh[4][8];
    #pragma unroll
    for (int g = 0; g < 4; ++g) {
        const int row = (g >> 1) * 256 + wave * 32 + (g & 1) * 16 + m16;
        const float* rp = w_hh + row * H_DIM;
        #pragma unroll
        for (int k = 0; k < 8; ++k) {
            const float* p = rp + k * 32 + quad * 8;
            whh[g][k] = pack8v(*(const floatx4*)p, *(const floatx4*)(p + 4));
        }
    }

    float brz[4], bhn[2], bxn[2];
    #pragma unroll
    for (int g = 0; g < 4; ++g) {
        const int u = wave * 32 + (g & 1) * 16 + m16;
        brz[g] = b_ih[(g >> 1) * 256 + u] + b_hh[(g >> 1) * 256 + u];
    }
    #pragma unroll
    for (int i = 0; i < 2; ++i) {
        const int u = wave * 32 + i * 16 + m16;
        bhn[i] = b_hh[512 + u];
        bxn[i] = b_ih[512 + u];
    }

    float h_old[8] = {0, 0, 0, 0, 0, 0, 0, 0};
    const float* xbase = x + (long)(wg * NB + m16) * T_LEN * I_DIM + quad * 8;
    const unsigned short* wib = &wih_ws[(wave * 6 * 2 * 64 + lane) * 8];

    __syncthreads();

    #pragma unroll 1
    for (int t = 0; t < T_LEN; ++t) {
        const float* xt = xbase + t * I_DIM;
        floatx4 x0 = *(const floatx4*)(xt);
        floatx4 x1 = *(const floatx4*)(xt + 4);
        floatx4 x2 = *(const floatx4*)(xt + 32);
        floatx4 x3 = *(const floatx4*)(xt + 36);
        short8 wi[12];
        #pragma unroll
        for (int j = 0; j < 12; ++j)
            wi[j] = *(const short8*)&wib[j * 64 * 8];

        floatx4 acc[4], an[2], xnl[2];
        #pragma unroll
        for (int g = 0; g < 4; ++g) acc[g] = (floatx4){0, 0, 0, 0};
        an[0] = an[1] = xnl[0] = xnl[1] = (floatx4){0, 0, 0, 0};

        const unsigned short* hb = &hbf[(t & 1) * 512 * 8];
        const unsigned short* wnb = &whn_lds[(wave * 2 * 8 * 64 + lane) * 8];
        #pragma unroll
        for (int k = 0; k < 8; ++k) {
            short8 af  = *(const short8*)&hb[(k * 64 + lane) * 8];
            short8 wn0 = *(const short8*)&wnb[(k * 64) * 8];
            short8 wn1 = *(const short8*)&wnb[((8 + k) * 64) * 8];
            acc[0] = __builtin_amdgcn_mfma_f32_16x16x32_bf16(af, whh[0][k], acc[0], 0, 0, 0);
            acc[1] = __builtin_amdgcn_mfma_f32_16x16x32_bf16(af, whh[1][k], acc[1], 0, 0, 0);
            acc[2] = __builtin_amdgcn_mfma_f32_16x16x32_bf16(af, whh[2][k], acc[2], 0, 0, 0);
            acc[3] = __builtin_amdgcn_mfma_f32_16x16x32_bf16(af, whh[3][k], acc[3], 0, 0, 0);
            an[0]  = __builtin_amdgcn_mfma_f32_16x16x32_bf16(af, wn0, an[0], 0, 0, 0);
            an[1]  = __builtin_amdgcn_mfma_f32_16x16x32_bf16(af, wn1, an[1], 0, 0, 0);
        }

        short8 xa = pack8v(x0, x1);
        acc[0] = __builtin_amdgcn_mfma_f32_16x16x32_bf16(xa, wi[0],  acc[0], 0, 0, 0);
        acc[1] = __builtin_amdgcn_mfma_f32_16x16x32_bf16(xa, wi[2],  acc[1], 0, 0, 0);
        acc[2] = __builtin_amdgcn_mfma_f32_16x16x32_bf16(xa, wi[4],  acc[2], 0, 0, 0);
        acc[3] = __builtin_amdgcn_mfma_f32_16x16x32_bf16(xa, wi[6],  acc[3], 0, 0, 0);
        xnl[0] = __builtin_amdgcn_mfma_f32_16x16x32_bf16(xa, wi[8],  xnl[0], 0, 0, 0);
        xnl[1] = __builtin_amdgcn_mfma_f32_16x16x32_bf16(xa, wi[10], xnl[1], 0, 0, 0);
        xa = pack8v(x2, x3);
        acc[0] = __builtin_amdgcn_mfma_f32_16x16x32_bf16(xa, wi[1],  acc[0], 0, 0, 0);
        acc[1] = __builtin_amdgcn_mfma_f32_16x16x32_bf16(xa, wi[3],  acc[1], 0, 0, 0);
        acc[2] = __builtin_amdgcn_mfma_f32_16x16x32_bf16(xa, wi[5],  acc[2], 0, 0, 0);
        acc[3] = __builtin_amdgcn_mfma_f32_16x16x32_bf16(xa, wi[7],  acc[3], 0, 0, 0);
        xnl[0] = __builtin_amdgcn_mfma_f32_16x16x32_bf16(xa, wi[9],  xnl[0], 0, 0, 0);
        xnl[1] = __builtin_amdgcn_mfma_f32_16x16x32_bf16(xa, wi[11], xnl[1], 0, 0, 0);

        unsigned short* hbn = &hbf[((t + 1) & 1) * 512 * 8];
        #pragma unroll
        for (int i = 0; i < 2; ++i) {
            #pragma unroll
            for (int r = 0; r < 4; ++r) {
                const int idx = i * 4 + r;
                float rr = sigm(acc[i][r] + brz[i]);
                float zz = sigm(acc[2 + i][r] + brz[2 + i]);
                float av = xnl[i][r] + bxn[i] + rr * (an[i][r] + bhn[i]);
                float nn = 1.0f - 2.0f / (1.0f + __expf(2.0f * av));
                float hn = (1.0f - zz) * nn + zz * h_old[idx];
                h_old[idx] = hn;
                hbn[(wave * 64 + (i * 2 + (m16 >> 3)) * 16 + quad * 4 + r) * 8
                    + (m16 & 7)] = f2bf(hn);
            }
        }
        __syncthreads();
    }

    __syncthreads();
    float* hfin = (float*)hbf;
    #pragma unroll
    for (int i = 0; i < 2; ++i)
        #pragma unroll
        for (int r = 0; r < 4; ++r)
            hfin[(quad * 4 + r) * 256 + wave * 32 + i * 16 + m16] =
                h_old[i * 4 + r];
    __syncthreads();

    const int m = tid >> 5, j = tid & 31;
    float s = 0.0f;
    #pragma unroll
    for (int c = 0; c < 8; ++c)
        s += hfin[m * 256 + j + c * 32] * w_lin[j + c * 32];
    #pragma unroll
    for (int d = 16; d > 0; d >>= 1) s += __shfl_down(s, d, 32);
    if (j == 0) {
        float p = sigm(s + b_lin[0]);
        const int b = wg * NB + m;
        out[2 * b]     = p;
        out[2 * b + 1] = 1.0f - p;
    }
}

extern "C" void kernel_launch(void* const* d_in, const int* in_sizes, int n_in,
                              void* d_out, int out_size, void* d_ws, size_t ws_size,
                              hipStream_t stream) {
    const float* x     = (const float*)d_in[0];
    const float* w_ih0 = (const float*)d_in[1];
    const float* w_hh0 = (const float*)d_in[2];
    const float* b_ih0 = (const float*)d_in[3];
    const float* b_hh0 = (const float*)d_in[4];
    // d_in[5..8]: layer-1 params — dead code in the reference
    const float* w_lin = (const float*)d_in[9];
    const float* b_lin = (const float*)d_in[10];
    float* out = (float*)d_out;
    unsigned short* wih_bf = (unsigned short*)d_ws;

    cvt_wih_kernel<<<24, 256, 0, stream>>>(w_ih0, wih_bf);

    if (ws_size >= XG_OFF + XG_BYTES) {
        unsigned short* xg = (unsigned short*)((char*)d_ws + XG_OFF);
        xg_kernel<<<1024, 256, 0, stream>>>(x, wih_bf, xg);
        gru_kernel_xg<<<NWG, 512, 0, stream>>>(xg, w_hh0, b_ih0, b_hh0,
                                               w_lin, b_lin, out);
    } else {
        gru_kernel<<<NWG, 512, 0, stream>>>(x, w_hh0, b_ih0, b_hh0, wih_bf,
                                            w_lin, b_lin, out);
    }
}

// Round 7
// 1785.647 us; speedup vs baseline: 1.0579x; 1.0579x over previous
//
#include <hip/hip_runtime.h>

// ---------------------------------------------------------------------------
// RegressionGRU round 7. Layer 1 of the reference is dead code; only layer-0's
// final hidden state feeds the output head. Persistent-RNN: 32 WGs x 512
// threads (8 waves); WG owns 16 batch rows for all 512 steps; wave owns 32
// hidden units x 3 gates.
//
// R6 lesson: ws_size < 403MB, the xg-precompute path never ran (fallback
// executed, counters identical to R5). R5 lesson: VALU-issue-bound from
// register shuttling -- in-loop wi/x loads pushed peak liveness ~280 over the
// 256-reg/wave unified budget (512-thread block = 2 waves/SIMD).
//
// This round: spill-free by construction, no ws-size gamble.
//   - whh r,z: register-resident 4 tiles x 8 k = 128 regs
//   - whh n:   LDS 128 KB (conflict-free blocked)
//   - wi[12]:  HOISTED out of the t-loop (loop-invariant; 48 persistent regs,
//              Av-class MFMA-B operands -> AGPR-eligible)
//   - biases:  bf16 in LDS (8 KB), loaded as one ds_read_b128 at gate time
//   - peak liveness (hg phase): 128+48+32+16+8+~8 = 240 <= 256
// LDS: 128K whn + 16K h dbuf + 8K bias = 152K <= 160K.
// ---------------------------------------------------------------------------

typedef __attribute__((ext_vector_type(8))) short short8;
typedef __attribute__((ext_vector_type(4))) float floatx4;

#define T_LEN 512
#define I_DIM 64
#define H_DIM 256
#define NB 16      // batch rows per WG (one MFMA M-tile)
#define NWG 32     // 512 / 16

__device__ __forceinline__ unsigned short f2bf(float f) {
    union { float f; unsigned u; } v; v.f = f;
    return (unsigned short)((v.u + 0x7FFFu + ((v.u >> 16) & 1u)) >> 16);
}

__device__ __forceinline__ float bf2f(unsigned short u) {
    union { unsigned u; float f; } v; v.u = ((unsigned)u) << 16;
    return v.f;
}

__device__ __forceinline__ short8 pack8v(floatx4 a, floatx4 b) {
    short8 r;
    r[0] = (short)f2bf(a[0]); r[1] = (short)f2bf(a[1]);
    r[2] = (short)f2bf(a[2]); r[3] = (short)f2bf(a[3]);
    r[4] = (short)f2bf(b[0]); r[5] = (short)f2bf(b[1]);
    r[6] = (short)f2bf(b[2]); r[7] = (short)f2bf(b[3]);
    return r;
}

__device__ __forceinline__ float sigm(float a) {
    return 1.0f / (1.0f + __expf(-a));
}

// w_ih fp32 [768x64] -> bf16 in d_ws, blocked: block ((w*6+g)*2+kx)*64+lane.
__global__ void cvt_wih_kernel(const float* __restrict__ w,
                               unsigned short* __restrict__ o) {
    int i = blockIdx.x * 256 + threadIdx.x;
    if (i < 6144) {
        const int l  = i & 63;
        const int kx = (i >> 6) & 1;
        const int g  = (i >> 7) % 6;
        const int wv = (i >> 7) / 6;
        const int row = (g >> 1) * 256 + wv * 32 + (g & 1) * 16 + (l & 15);
        const int col = kx * 32 + (l >> 4) * 8;
        const float* p = w + row * I_DIM + col;
        *(short8*)&o[i * 8] = pack8v(*(const floatx4*)p,
                                     *(const floatx4*)(p + 4));
    }
}

__global__ __launch_bounds__(512, 1) void gru_kernel(
    const float* __restrict__ x,        // [512, 512, 64]
    const float* __restrict__ w_hh,     // [768, 256]
    const float* __restrict__ b_ih,     // [768]
    const float* __restrict__ b_hh,     // [768]
    const unsigned short* __restrict__ wih_ws, // [6144*8] bf16, blocked
    const float* __restrict__ w_lin,    // [256]
    const float* __restrict__ b_lin,    // [1]
    float* __restrict__ out)            // [1024]
{
    __shared__ __align__(16) unsigned short whn_lds[8192 * 8]; // 128 KB
    __shared__ __align__(16) unsigned short hbf[1024 * 8];     // 16 KB dbuf
    __shared__ __align__(16) unsigned short bias_lds[512 * 8]; // 8 KB bf16

    const int tid  = threadIdx.x;
    const int wave = tid >> 6;       // 0..7: owns units wave*32..wave*32+31
    const int lane = tid & 63;
    const int m16  = lane & 15;      // batch row (A) / unit-in-tile (B/C col)
    const int quad = lane >> 4;      // K-octet selector / C row-group
    const int wg   = blockIdx.x;

    // ---- preload whh n-gate -> LDS, blocked: block ((w*2+g)*8+k)*64+lane --
    for (int b = tid; b < 8192; b += 512) {
        const int l = b & 63;
        const int k = (b >> 6) & 7;
        const int g = (b >> 9) & 1;
        const int w = b >> 10;
        const int row = 512 + w * 32 + g * 16 + (l & 15);
        const int col = k * 32 + (l >> 4) * 8;
        const float* p = w_hh + row * H_DIM + col;
        *(short8*)&whn_lds[b * 8] = pack8v(*(const floatx4*)p,
                                           *(const floatx4*)(p + 4));
    }
    for (int b = tid; b < 1024; b += 512)
        *(short8*)&hbf[b * 8] = (short8)0;   // h0 = 0 (both buffers)

    // ---- per-thread bf16 bias vector (one ds_read_b128 at gate time) -----
    {
        const int u0 = wave * 32 + m16, u1 = u0 + 16;
        unsigned short* bl = &bias_lds[tid * 8];
        bl[0] = f2bf(b_ih[u0] + b_hh[u0]);               // r  i0
        bl[1] = f2bf(b_ih[u1] + b_hh[u1]);               // r  i1
        bl[2] = f2bf(b_ih[256 + u0] + b_hh[256 + u0]);   // z  i0
        bl[3] = f2bf(b_ih[256 + u1] + b_hh[256 + u1]);   // z  i1
        bl[4] = f2bf(b_hh[512 + u0]);                    // hn i0
        bl[5] = f2bf(b_hh[512 + u1]);                    // hn i1
        bl[6] = f2bf(b_ih[512 + u0]);                    // xn i0
        bl[7] = f2bf(b_ih[512 + u1]);                    // xn i1
    }

    // ---- persistent w_hh r,z B-fragments: 4 tiles x 8 K = 128 regs -------
    // tile g: 0=r/i0 1=r/i1 2=z/i0 3=z/i1
    short8 whh[4][8];
    #pragma unroll
    for (int g = 0; g < 4; ++g) {
        const int row = (g >> 1) * 256 + wave * 32 + (g & 1) * 16 + m16;
        const float* rp = w_hh + row * H_DIM;
        #pragma unroll
        for (int k = 0; k < 8; ++k) {
            const float* p = rp + k * 32 + quad * 8;
            whh[g][k] = pack8v(*(const floatx4*)p, *(const floatx4*)(p + 4));
        }
    }

    // ---- persistent w_ih B-fragments (HOISTED, loop-invariant): 48 regs --
    // j = g*2 + kx; tiles g: 0=r/i0 1=r/i1 2=z/i0 3=z/i1 4=n/i0 5=n/i1
    short8 wi[12];
    {
        const unsigned short* wib = &wih_ws[(wave * 6 * 2 * 64 + lane) * 8];
        #pragma unroll
        for (int j = 0; j < 12; ++j)
            wi[j] = *(const short8*)&wib[j * 64 * 8];
    }

    float h_old[8] = {0, 0, 0, 0, 0, 0, 0, 0};  // fp32 recurrence carry

    const float* xbase = x + (long)(wg * NB + m16) * T_LEN * I_DIM + quad * 8;

    __syncthreads();

    #pragma unroll 1
    for (int t = 0; t < T_LEN; ++t) {
        // ---- issue x(t) loads first (consumed after hg; latency hidden) --
        const float* xt = xbase + t * I_DIM;
        floatx4 x0 = *(const floatx4*)(xt);
        floatx4 x1 = *(const floatx4*)(xt + 4);
        floatx4 x2 = *(const floatx4*)(xt + 32);
        floatx4 x3 = *(const floatx4*)(xt + 36);

        floatx4 acc[4], an[2], xnl[2];
        #pragma unroll
        for (int g = 0; g < 4; ++g) acc[g] = (floatx4){0, 0, 0, 0};
        an[0] = an[1] = xnl[0] = xnl[1] = (floatx4){0, 0, 0, 0};

        // ---- hg: h @ w_hh^T; r,z from registers, n from LDS --------------
        const unsigned short* hb  = &hbf[(t & 1) * 512 * 8];
        const unsigned short* wnb = &whn_lds[(wave * 2 * 8 * 64 + lane) * 8];
        #pragma unroll
        for (int k = 0; k < 8; ++k) {
            short8 af  = *(const short8*)&hb[(k * 64 + lane) * 8];
            short8 wn0 = *(const short8*)&wnb[(k * 64) * 8];
            short8 wn1 = *(const short8*)&wnb[((8 + k) * 64) * 8];
            acc[0] = __builtin_amdgcn_mfma_f32_16x16x32_bf16(af, whh[0][k], acc[0], 0, 0, 0);
            acc[1] = __builtin_amdgcn_mfma_f32_16x16x32_bf16(af, whh[1][k], acc[1], 0, 0, 0);
            acc[2] = __builtin_amdgcn_mfma_f32_16x16x32_bf16(af, whh[2][k], acc[2], 0, 0, 0);
            acc[3] = __builtin_amdgcn_mfma_f32_16x16x32_bf16(af, whh[3][k], acc[3], 0, 0, 0);
            an[0]  = __builtin_amdgcn_mfma_f32_16x16x32_bf16(af, wn0, an[0], 0, 0, 0);
            an[1]  = __builtin_amdgcn_mfma_f32_16x16x32_bf16(af, wn1, an[1], 0, 0, 0);
        }

        // ---- xg: x_t @ w_ih^T (wi persistent in registers) ---------------
        short8 xa = pack8v(x0, x1);            // kx = 0
        acc[0] = __builtin_amdgcn_mfma_f32_16x16x32_bf16(xa, wi[0],  acc[0], 0, 0, 0);
        acc[1] = __builtin_amdgcn_mfma_f32_16x16x32_bf16(xa, wi[2],  acc[1], 0, 0, 0);
        acc[2] = __builtin_amdgcn_mfma_f32_16x16x32_bf16(xa, wi[4],  acc[2], 0, 0, 0);
        acc[3] = __builtin_amdgcn_mfma_f32_16x16x32_bf16(xa, wi[6],  acc[3], 0, 0, 0);
        xnl[0] = __builtin_amdgcn_mfma_f32_16x16x32_bf16(xa, wi[8],  xnl[0], 0, 0, 0);
        xnl[1] = __builtin_amdgcn_mfma_f32_16x16x32_bf16(xa, wi[10], xnl[1], 0, 0, 0);
        xa = pack8v(x2, x3);                   // kx = 1
        acc[0] = __builtin_amdgcn_mfma_f32_16x16x32_bf16(xa, wi[1],  acc[0], 0, 0, 0);
        acc[1] = __builtin_amdgcn_mfma_f32_16x16x32_bf16(xa, wi[3],  acc[1], 0, 0, 0);
        acc[2] = __builtin_amdgcn_mfma_f32_16x16x32_bf16(xa, wi[5],  acc[2], 0, 0, 0);
        acc[3] = __builtin_amdgcn_mfma_f32_16x16x32_bf16(xa, wi[7],  acc[3], 0, 0, 0);
        xnl[0] = __builtin_amdgcn_mfma_f32_16x16x32_bf16(xa, wi[9],  xnl[0], 0, 0, 0);
        xnl[1] = __builtin_amdgcn_mfma_f32_16x16x32_bf16(xa, wi[11], xnl[1], 0, 0, 0);

        // ---- gates + h update (lane-local; C: col=m16, row=quad*4+r) -----
        short8 bv = *(const short8*)&bias_lds[tid * 8];
        unsigned short* hbn = &hbf[((t + 1) & 1) * 512 * 8];
        #pragma unroll
        for (int i = 0; i < 2; ++i) {
            #pragma unroll
            for (int r = 0; r < 4; ++r) {
                const int idx = i * 4 + r;
                float rr = sigm(acc[i][r]     + bf2f((unsigned short)bv[i]));
                float zz = sigm(acc[2 + i][r] + bf2f((unsigned short)bv[2 + i]));
                float av = xnl[i][r] + bf2f((unsigned short)bv[6 + i])
                         + rr * (an[i][r] + bf2f((unsigned short)bv[4 + i]));
                float nn = 1.0f - 2.0f / (1.0f + __expf(2.0f * av)); // tanh
                float hn = (1.0f - zz) * nn + zz * h_old[idx];
                h_old[idx] = hn;
                hbn[(wave * 64 + (i * 2 + (m16 >> 3)) * 16 + quad * 4 + r) * 8
                    + (m16 & 7)] = f2bf(hn);
            }
        }
        __syncthreads();  // h(t+1) visible; prev buffer free for overwrite
    }

    // ---- epilogue: p = sigmoid(h_last . w_lin + b) -----------------------
    __syncthreads();
    float* hfin = (float*)hbf;  // reuse 16KB as fp32 h[16][256]
    #pragma unroll
    for (int i = 0; i < 2; ++i)
        #pragma unroll
        for (int r = 0; r < 4; ++r)
            hfin[(quad * 4 + r) * 256 + wave * 32 + i * 16 + m16] =
                h_old[i * 4 + r];
    __syncthreads();

    const int m = tid >> 5, j = tid & 31;  // 32 threads per batch row
    float s = 0.0f;
    #pragma unroll
    for (int c = 0; c < 8; ++c)
        s += hfin[m * 256 + j + c * 32] * w_lin[j + c * 32];
    #pragma unroll
    for (int d = 16; d > 0; d >>= 1) s += __shfl_down(s, d, 32);
    if (j == 0) {
        float p = sigm(s + b_lin[0]);
        const int b = wg * NB + m;
        out[2 * b]     = p;
        out[2 * b + 1] = 1.0f - p;
    }
}

extern "C" void kernel_launch(void* const* d_in, const int* in_sizes, int n_in,
                              void* d_out, int out_size, void* d_ws, size_t ws_size,
                              hipStream_t stream) {
    const float* x     = (const float*)d_in[0];
    const float* w_ih0 = (const float*)d_in[1];
    const float* w_hh0 = (const float*)d_in[2];
    const float* b_ih0 = (const float*)d_in[3];
    const float* b_hh0 = (const float*)d_in[4];
    // d_in[5..8]: layer-1 params — dead code in the reference
    const float* w_lin = (const float*)d_in[9];
    const float* b_lin = (const float*)d_in[10];
    float* out = (float*)d_out;
    unsigned short* wih_bf = (unsigned short*)d_ws;  // 96 KB of workspace

    cvt_wih_kernel<<<24, 256, 0, stream>>>(w_ih0, wih_bf);
    gru_kernel<<<NWG, 512, 0, stream>>>(x, w_hh0, b_ih0, b_hh0, wih_bf,
                                        w_lin, b_lin, out);
}